// Round 12
// baseline (290.499 us; speedup 1.0000x reference)
//
#include <hip/hip_runtime.h>

typedef unsigned short u16;
typedef unsigned int   u32;
typedef u16  u16x8 __attribute__((ext_vector_type(8)));
typedef u16  u16x4 __attribute__((ext_vector_type(4)));
typedef float f32x4 __attribute__((ext_vector_type(4)));
typedef __bf16 bf16x8 __attribute__((ext_vector_type(8)));

#define SEQ   512
#define DIM   512
#define DHEAD 64
#define M_ROWS 16384   // 4*8*512

#define AS1 __attribute__((address_space(1)))
#define AS3 __attribute__((address_space(3)))
// async global->LDS, 16B per lane, LDS dest = wave-uniform base + lane*16
#define GLL16(gp, lp) __builtin_amdgcn_global_load_lds((const AS1 void*)(gp), (AS3 void*)(lp), 16, 0, 0)

// counted-vmcnt barrier pair for the 2-phase pipeline (prefetch stays in
// flight across the barrier; NEVER vmcnt(0) in-loop)
#define WAIT_VM_BAR(LIT) do { asm volatile("s_waitcnt vmcnt(" LIT ")" ::: "memory"); __builtin_amdgcn_s_barrier(); } while (0)
#define LGKM_BAR()       do { asm volatile("s_waitcnt lgkmcnt(0)" ::: "memory"); __builtin_amdgcn_s_barrier(); } while (0)

__device__ __forceinline__ u16 f2b(float f) {
  u32 x = __builtin_bit_cast(u32, f);
  return (u16)((x + 0x7fffu + ((x >> 16) & 1u)) >> 16);
}

// 8x fp32 -> bf16x8 (RNE, compiler emits v_cvt_pk_bf16_f32 pairs)
__device__ __forceinline__ bf16x8 cvt8(float4 a, float4 b) {
  bf16x8 r;
  r[0] = (__bf16)a.x; r[1] = (__bf16)a.y; r[2] = (__bf16)a.z; r[3] = (__bf16)a.w;
  r[4] = (__bf16)b.x; r[5] = (__bf16)b.y; r[6] = (__bf16)b.z; r[7] = (__bf16)b.w;
  return r;
}

// ---------------------------------------------------------------------------
// Kernel 0: prep = weight transpose ONLY, fp32 [K,N] -> bf16 [N,K], 1024
// blocks. Input fp32->bf16 conversion is now fused into gemm_qkv (direct
// fp32 fragment loads), deleting a 200 MB streaming pass.
// ---------------------------------------------------------------------------
__global__ __launch_bounds__(256) void prep(const float* __restrict__ Wq,
                                            const float* __restrict__ Wk,
                                            const float* __restrict__ Wv,
                                            const float* __restrict__ Wo,
                                            u16* __restrict__ wout) {
  __shared__ float tile[32][33];
  const int bid = blockIdx.x;          // 0..1023
  const int z = bid >> 8;              // weight index 0..3
  const int t = bid & 255;
  const int n0 = (t & 15) * 32;
  const int k0 = (t >> 4) * 32;
  const int tid = threadIdx.x;
  const int tx = tid & 31, ty = tid >> 5;
  const float* W = (z == 0) ? Wq : (z == 1) ? Wk : (z == 2) ? Wv : Wo;
#pragma unroll
  for (int i = 0; i < 4; i++) {
    int r = ty + i * 8;
    tile[r][tx] = W[(k0 + r) * DIM + n0 + tx];
  }
  __syncthreads();
  u16* o = wout + (size_t)z * DIM * DIM;
#pragma unroll
  for (int i = 0; i < 4; i++) {
    int r = ty + i * 8;
    o[(n0 + r) * DIM + k0 + tx] = f2b(tile[tx][r]);
  }
}

// ---------------------------------------------------------------------------
// Kernel 1: fused Q/K/V^T projection GEMM — LDS-FREE, BARRIER-FREE.
// Every operand fragment is loaded directly from global/L2 (the pattern
// attn already uses for Q): bf16 weights as bf16x8, fp32 inputs as two
// float4 + in-register cvt (RNE — numerically identical to the old prep
// path). No __syncthreads anywhere => the compiler software-pipelines
// loads across K-steps, which every barrier structure defeated. Redundant
// panel reads hit L2 (XCD swizzle keeps panel groups co-located).
// 128x128 tile, 4 waves 2x2, each 64x64; grid 512x3.
//  z=0: Qb = Qin_f32 @ Wq   z=1: Kb = KVin_f32 @ Wk
//  z=2: Vt[512,M] = Wvt . KVin_f32^T
// ---------------------------------------------------------------------------
__global__ __launch_bounds__(256, 2) void gemm_qkv(const float* __restrict__ Qin,
                                                   const float* __restrict__ KVin,
                                                   const u16* __restrict__ Wqt,
                                                   const u16* __restrict__ Wkt,
                                                   const u16* __restrict__ Wvt,
                                                   u16* __restrict__ Qb,
                                                   u16* __restrict__ Kb,
                                                   u16* __restrict__ Vt) {
  const int tid = threadIdx.x;
  const int lane = tid & 63;
  const int w = tid >> 6;
  const int l15 = lane & 15;
  const int quad = lane >> 4;
  const int z = blockIdx.z;
  const int d = blockIdx.x;                  // 0..511
  const int bid = (d & 7) * 64 + (d >> 3);   // XCD swizzle, bijective on 512
  const int wr = (w >> 1) * 64, wc = (w & 1) * 64;

  f32x4 acc[4][4] = {};

  if (z < 2) {
    const float* A = z ? KVin : Qin;
    const u16*   B = z ? Wkt : Wqt;
    const int gm = (bid >> 2) * 128;       // 128 m-tiles
    const int gn = (bid & 3) * 128;        // 4 n-tiles
#pragma unroll 2
    for (int k0 = 0; k0 < DIM; k0 += 32) {
      bf16x8 af[4], bfr[4];
#pragma unroll
      for (int mt = 0; mt < 4; mt++) {
        const float* ap = &A[(size_t)(gm + wr + mt * 16 + l15) * DIM + k0 + quad * 8];
        float4 x = *reinterpret_cast<const float4*>(ap);
        float4 y = *reinterpret_cast<const float4*>(ap + 4);
        af[mt] = cvt8(x, y);
      }
#pragma unroll
      for (int nt = 0; nt < 4; nt++)
        bfr[nt] = *reinterpret_cast<const bf16x8*>(&B[(size_t)(gn + wc + nt * 16 + l15) * DIM + k0 + quad * 8]);
#pragma unroll
      for (int mt = 0; mt < 4; mt++)
#pragma unroll
        for (int nt = 0; nt < 4; nt++)
          acc[mt][nt] = __builtin_amdgcn_mfma_f32_16x16x32_bf16(af[mt], bfr[nt], acc[mt][nt], 0, 0, 0);
    }
    u16* C = (z == 0) ? Qb : Kb;
#pragma unroll
    for (int mt = 0; mt < 4; mt++)
#pragma unroll
      for (int nt = 0; nt < 4; nt++)
#pragma unroll
        for (int r = 0; r < 4; r++)
          C[(size_t)(gm + wr + mt * 16 + quad * 4 + r) * DIM + gn + wc + nt * 16 + l15] = f2b(acc[mt][nt][r]);
  } else {
    const int gm = (bid & 3) * 128;        // 4 m-tiles (Wvt rows = d)
    const int gn = (bid >> 2) * 128;       // 128 n-tiles (KVin rows)
#pragma unroll 2
    for (int k0 = 0; k0 < DIM; k0 += 32) {
      bf16x8 af[4], bfr[4];
#pragma unroll
      for (int mt = 0; mt < 4; mt++)
        af[mt] = *reinterpret_cast<const bf16x8*>(&Wvt[(size_t)(gm + wr + mt * 16 + l15) * DIM + k0 + quad * 8]);
#pragma unroll
      for (int nt = 0; nt < 4; nt++) {
        const float* bp = &KVin[(size_t)(gn + wc + nt * 16 + l15) * DIM + k0 + quad * 8];
        float4 x = *reinterpret_cast<const float4*>(bp);
        float4 y = *reinterpret_cast<const float4*>(bp + 4);
        bfr[nt] = cvt8(x, y);
      }
#pragma unroll
      for (int mt = 0; mt < 4; mt++)
#pragma unroll
        for (int nt = 0; nt < 4; nt++)
          acc[mt][nt] = __builtin_amdgcn_mfma_f32_16x16x32_bf16(af[mt], bfr[nt], acc[mt][nt], 0, 0, 0);
    }
#pragma unroll
    for (int mt = 0; mt < 4; mt++)
#pragma unroll
      for (int nt = 0; nt < 4; nt++)
#pragma unroll
        for (int r = 0; r < 4; r++)
          Vt[(size_t)(gm + wr + mt * 16 + quad * 4 + r) * M_ROWS + gn + wc + nt * 16 + l15] = f2b(acc[mt][nt][r]);
  }
}

// ---------------------------------------------------------------------------
// Kernel 2: flash attention — R9 VERBATIM (GLL16 single-buffer KVBLK=64,
// per-g Pq planes, no fences, XCD swizzle, static-base exp2 softmax).
// ---------------------------------------------------------------------------
__global__ __launch_bounds__(256) void attn(const u16* __restrict__ Qb,
                                            const u16* __restrict__ Kb,
                                            const u16* __restrict__ Vtg,
                                            u16* __restrict__ Ob) {
  __shared__ __attribute__((aligned(16))) u16 Ks[2 * 64 * 32];    // [kd-plane][key][32]
  __shared__ __attribute__((aligned(16))) u16 Vs[2 * 64 * 32];    // [key-plane][d][32]
  __shared__ __attribute__((aligned(16))) u16 Pq[4][2][16 * 72];  // per-wave, per-g

  const int tid = threadIdx.x;
  const int lane = tid & 63;
  const int w = tid >> 6;
  const int l15 = lane & 15;
  const int quad = lane >> 4;
  const int srow = lane >> 2;
  const int scol = (lane & 3) * 8;

  // XCD swizzle: hw index d -> logical bid = (d&7)*128 + (d>>3). Bijective on
  // [0,1024). Panel group {4p..4p+3} maps to hw indices differing by 8 ->
  // same XCD under round-robin dispatch. Perf-only (any mapping is correct).
  const int d = blockIdx.x;
  const int bid = (d & 7) * 128 + (d >> 3);
  const int qt = bid & 3;            // 4 q-tiles of 128 rows
  const int bhp = bid >> 2;
  const int h = bhp & 7;
  const int bp = bhp >> 3;           // 0..31
  const int qrow0 = bp * SEQ + qt * 128;
  const int col0 = h * DHEAD;

  const float SCL = 0.18033688011112042f;   // 0.125 * log2(e)

  // Q fragments direct from global (B-operand layout: lane holds q=l15)
  bf16x8 qf[2][2];
#pragma unroll
  for (int g = 0; g < 2; g++)
#pragma unroll
    for (int kd = 0; kd < 2; kd++)
      qf[g][kd] = *reinterpret_cast<const bf16x8*>(
          &Qb[(size_t)(qrow0 + w * 32 + g * 16 + l15) * DIM + col0 + kd * 32 + quad * 8]);

  float l_[2] = {0.0f, 0.0f};
  f32x4 o[2][4] = {};

  for (int j = 0; j < 8; j++) {
    __syncthreads();
    const int krow0 = bp * SEQ + j * 64;
    // K staging: 8 GLL16 (plane=kd 0..1, 16-key chunk 0..3); wave w: t=2w..2w+1
#pragma unroll
    for (int i = 0; i < 2; i++) {
      int t = w * 2 + i;
      int plane = t & 1, chunk = t >> 1;
      GLL16(&Kb[(size_t)(krow0 + chunk * 16 + srow) * DIM + col0 + plane * 32 + scol],
            &Ks[plane * 2048 + chunk * 512]);
    }
    // V staging: 8 GLL16 (plane=32-key chunk 0..1, chunk=16-d chunk 0..3)
#pragma unroll
    for (int i = 0; i < 2; i++) {
      int t = w * 2 + i;
      int plane = t & 1, chunk = t >> 1;
      GLL16(&Vtg[(size_t)(col0 + chunk * 16 + srow) * M_ROWS + krow0 + plane * 32 + scol],
            &Vs[plane * 2048 + chunk * 512]);
    }
    __syncthreads();

#pragma unroll
    for (int g = 0; g < 2; g++) {
      // S^T = K*Q^T : 4 key-tiles of 16; D[key][q=l15]; scale has log2e folded
      f32x4 st[4];
#pragma unroll
      for (int ct = 0; ct < 4; ct++) {
        f32x4 z = {};
#pragma unroll
        for (int kd = 0; kd < 2; kd++) {
          bf16x8 kf = *reinterpret_cast<const bf16x8*>(&Ks[kd * 2048 + (ct * 16 + l15) * 32 + quad * 8]);
          z = __builtin_amdgcn_mfma_f32_16x16x32_bf16(kf, qf[g][kd], z, 0, 0, 0);
        }
        st[ct] = z * SCL;
      }

      // static-base softmax: P = 2^st directly (no max track, no rescale);
      // row-sum reduced across quads (q=l15 holds 16 keys/lane)
      float rs = 0.0f;
#pragma unroll
      for (int ct = 0; ct < 4; ct++)
#pragma unroll
        for (int r = 0; r < 4; r++) {
          float pv = __builtin_amdgcn_exp2f(st[ct][r]);
          st[ct][r] = pv;
          rs += pv;
        }
      rs += __shfl_xor(rs, 16);
      rs += __shfl_xor(rs, 32);
      l_[g] += rs;

      // P^T (C-layout) -> Pq[w][g][q][key], packed b64 stores. No fence:
      // per-g buffer => no reuse hazard; same-wave store->read ordering is
      // a visible data dependence the compiler handles with lgkmcnt(N).
#pragma unroll
      for (int ct = 0; ct < 4; ct++) {
        u16x4 pk;
#pragma unroll
        for (int e = 0; e < 4; e++) pk[e] = f2b(st[ct][e]);
        *reinterpret_cast<u16x4*>(&Pq[w][g][l15 * 72 + ct * 16 + quad * 4]) = pk;
      }

      // O += P*V : A = Pq[w][g][q=l15][key], B = Vs plane c2 [d][key-chunk]
#pragma unroll
      for (int c2 = 0; c2 < 2; c2++) {
        bf16x8 af = *reinterpret_cast<const bf16x8*>(&Pq[w][g][l15 * 72 + c2 * 32 + quad * 8]);
#pragma unroll
        for (int nt = 0; nt < 4; nt++) {
          bf16x8 bv = *reinterpret_cast<const bf16x8*>(&Vs[c2 * 2048 + (nt * 16 + l15) * 32 + quad * 8]);
          o[g][nt] = __builtin_amdgcn_mfma_f32_16x16x32_bf16(af, bv, o[g][nt], 0, 0, 0);
        }
      }
    }
  }

  // epilogue: normalize and write bf16 [M,512]
#pragma unroll
  for (int g = 0; g < 2; g++) {
    float inv = 1.0f / l_[g];
#pragma unroll
    for (int r = 0; r < 4; r++) {
      float lr = __shfl(inv, quad * 4 + r);
      int row = qrow0 + w * 32 + g * 16 + quad * 4 + r;
#pragma unroll
      for (int nt = 0; nt < 4; nt++)
        Ob[(size_t)row * DIM + col0 + nt * 16 + l15] = f2b(o[g][nt][r] * lr);
    }
  }
}

// ---------------------------------------------------------------------------
// Kernel 3: output GEMM, 2-phase double-buffered staging + XCD swizzle
// (1-D grid 512; blocks sharing an Ob A-panel were consecutive in x).
// fp32 epilogue + bias.
// ---------------------------------------------------------------------------
__global__ __launch_bounds__(256) void gemm_out(const u16* __restrict__ Ab,
                                                const u16* __restrict__ Bt,
                                                const float* __restrict__ bias,
                                                float* __restrict__ C) {
  __shared__ __attribute__((aligned(16))) u16 As[2][128 * 32];
  __shared__ __attribute__((aligned(16))) u16 Bs[2][128 * 32];
  const int tid = threadIdx.x;
  const int lane = tid & 63;
  const int w = tid >> 6;
  const int l15 = lane & 15;
  const int quad = lane >> 4;
  const int d = blockIdx.x;                  // 0..511
  const int bid = (d & 7) * 64 + (d >> 3);   // XCD swizzle, bijective on 512
  const int gn = (bid & 3) * 128;
  const int gm = (bid >> 2) * 128;
  const int wr = (w >> 1) * 64, wc = (w & 1) * 64;
  const int srow = lane >> 2;
  const int scol = (lane & 3) * 8;

  f32x4 acc[4][4] = {};

  // stage K-step kk into buffer b: 4 GLL16 per wave (2 A + 2 B)
  auto stage = [&](int kk, int b) {
    const int k0 = kk * 32;
#pragma unroll
    for (int i = 0; i < 2; i++) {
      int r0 = w * 32 + i * 16;
      GLL16(&Ab[(size_t)(gm + r0 + srow) * DIM + k0 + scol], &As[b][r0 * 32]);
      GLL16(&Bt[(size_t)(gn + r0 + srow) * DIM + k0 + scol], &Bs[b][r0 * 32]);
    }
  };

  stage(0, 0);
  for (int kk = 0; kk < 16; kk++) {
    const int cur = kk & 1;
    if (kk < 15) {
      stage(kk + 1, cur ^ 1);
      WAIT_VM_BAR("4");
    } else {
      WAIT_VM_BAR("0");
    }

    bf16x8 af[4], bfr[4];
#pragma unroll
    for (int mt = 0; mt < 4; mt++)
      af[mt] = *reinterpret_cast<const bf16x8*>(&As[cur][(wr + mt * 16 + l15) * 32 + quad * 8]);
#pragma unroll
    for (int nt = 0; nt < 4; nt++)
      bfr[nt] = *reinterpret_cast<const bf16x8*>(&Bs[cur][(wc + nt * 16 + l15) * 32 + quad * 8]);
#pragma unroll
    for (int mt = 0; mt < 4; mt++)
#pragma unroll
      for (int nt = 0; nt < 4; nt++)
        acc[mt][nt] = __builtin_amdgcn_mfma_f32_16x16x32_bf16(af[mt], bfr[nt], acc[mt][nt], 0, 0, 0);

    LGKM_BAR();
  }

#pragma unroll
  for (int mt = 0; mt < 4; mt++)
#pragma unroll
    for (int nt = 0; nt < 4; nt++) {
      float bcol = bias[gn + wc + nt * 16 + l15];
#pragma unroll
      for (int r = 0; r < 4; r++)
        C[(size_t)(gm + wr + mt * 16 + quad * 4 + r) * DIM + gn + wc + nt * 16 + l15] = acc[mt][nt][r] + bcol;
    }
}

// ---------------------------------------------------------------------------
extern "C" void kernel_launch(void* const* d_in, const int* in_sizes, int n_in,
                              void* d_out, int out_size, void* d_ws, size_t ws_size,
                              hipStream_t stream) {
  const float* q_in  = (const float*)d_in[0];
  const float* kv_in = (const float*)d_in[1];
  const float* Wq    = (const float*)d_in[2];
  const float* Wk    = (const float*)d_in[3];
  const float* Wv    = (const float*)d_in[4];
  const float* Wo    = (const float*)d_in[5];
  const float* bo    = (const float*)d_in[6];
  float* out = (float*)d_out;

  u16* ws = (u16*)d_ws;
  u16* Wqt = ws;
  u16* Wkt = ws + 262144;
  u16* Wvt = ws + 524288;
  u16* Wot = ws + 786432;
  u16* Qb  = ws + 1048576;
  u16* Kb  = Qb + (size_t)M_ROWS * DIM;
  u16* Vtg = Kb + (size_t)M_ROWS * DIM;
  u16* Ob  = Vtg + (size_t)M_ROWS * DIM;

  prep<<<dim3(1024), 256, 0, stream>>>(Wq, Wk, Wv, Wo, ws);
  gemm_qkv<<<dim3(512, 1, 3), 256, 0, stream>>>(q_in, kv_in, Wqt, Wkt, Wvt, Qb, Kb, Vtg);
  attn<<<dim3(1024), 256, 0, stream>>>(Qb, Kb, Vtg, Ob);
  gemm_out<<<dim3(512), 256, 0, stream>>>(Ob, Wot, bo, out);
}

// Round 13
// 198.016 us; speedup vs baseline: 1.4670x; 1.4670x over previous
//
#include <hip/hip_runtime.h>

typedef unsigned short u16;
typedef unsigned int   u32;
typedef u16  u16x8 __attribute__((ext_vector_type(8)));
typedef u16  u16x4 __attribute__((ext_vector_type(4)));
typedef float f32x4 __attribute__((ext_vector_type(4)));
typedef __bf16 bf16x8 __attribute__((ext_vector_type(8)));

#define SEQ   512
#define DIM   512
#define DHEAD 64
#define M_ROWS 16384   // 4*8*512

#define AS1 __attribute__((address_space(1)))
#define AS3 __attribute__((address_space(3)))
// async global->LDS, 16B per lane, LDS dest = wave-uniform base + lane*16
#define GLL16(gp, lp) __builtin_amdgcn_global_load_lds((const AS1 void*)(gp), (AS3 void*)(lp), 16, 0, 0)

// counted-vmcnt barrier pair for the 2-phase pipeline (prefetch stays in
// flight across the barrier; NEVER vmcnt(0) in-loop)
#define WAIT_VM_BAR(LIT) do { asm volatile("s_waitcnt vmcnt(" LIT ")" ::: "memory"); __builtin_amdgcn_s_barrier(); } while (0)
#define LGKM_BAR()       do { asm volatile("s_waitcnt lgkmcnt(0)" ::: "memory"); __builtin_amdgcn_s_barrier(); } while (0)

__device__ __forceinline__ u16 f2b(float f) {
  u32 x = __builtin_bit_cast(u32, f);
  return (u16)((x + 0x7fffu + ((x >> 16) & 1u)) >> 16);
}

// ---------------------------------------------------------------------------
// Kernel 0: prep = convert inputs fp32->bf16 (blocks 0..8191) + weight
// transpose fp32 [K,N] -> bf16 [N,K] (blocks 8192..9215). One launch.
// (R12's attempt to delete the conversion pass by direct fp32 fragment
// loads in gemm_qkv regressed 40->152 us: without LDS staging the fragment
// loads are 16-way scattered and unpipelined. Staging IS the latency hider.)
// ---------------------------------------------------------------------------
__global__ __launch_bounds__(256) void prep(const float* __restrict__ q,
                                            const float* __restrict__ kv,
                                            const float* __restrict__ Wq,
                                            const float* __restrict__ Wk,
                                            const float* __restrict__ Wv,
                                            const float* __restrict__ Wo,
                                            u16* __restrict__ qb,
                                            u16* __restrict__ kvb,
                                            u16* __restrict__ wout) {
  __shared__ float tile[32][33];
  const int bid = blockIdx.x;
  if (bid < 8192) {
    const float* src = (bid >= 4096) ? kv : q;
    u16* dst = (bid >= 4096) ? kvb : qb;
    size_t i = ((size_t)(bid & 4095) * 256 + threadIdx.x) * 8;
    float4 a = *reinterpret_cast<const float4*>(&src[i]);
    float4 b = *reinterpret_cast<const float4*>(&src[i + 4]);
    u16x8 o;
    o[0] = f2b(a.x); o[1] = f2b(a.y); o[2] = f2b(a.z); o[3] = f2b(a.w);
    o[4] = f2b(b.x); o[5] = f2b(b.y); o[6] = f2b(b.z); o[7] = f2b(b.w);
    *reinterpret_cast<u16x8*>(&dst[i]) = o;
  } else {
    const int rem = bid - 8192;          // 0..1023
    const int z = rem >> 8;              // weight index 0..3
    const int t = rem & 255;
    const int n0 = (t & 15) * 32;
    const int k0 = (t >> 4) * 32;
    const int tid = threadIdx.x;
    const int tx = tid & 31, ty = tid >> 5;
    const float* W = (z == 0) ? Wq : (z == 1) ? Wk : (z == 2) ? Wv : Wo;
#pragma unroll
    for (int i = 0; i < 4; i++) {
      int r = ty + i * 8;
      tile[r][tx] = W[(k0 + r) * DIM + n0 + tx];
    }
    __syncthreads();
    u16* o = wout + (size_t)z * DIM * DIM;
#pragma unroll
    for (int i = 0; i < 4; i++) {
      int r = ty + i * 8;
      o[(n0 + r) * DIM + k0 + tx] = f2b(tile[tx][r]);
    }
  }
}

// ---------------------------------------------------------------------------
// Kernel 1: fused Q/K/V^T projection GEMM, all-bf16, GLL16 staging.
// 128x128 tile (measured-best for this 2-barrier 2-phase structure),
// 4 waves in 2x2, each wave 64x64 (4x4 MFMA 16x16x32); BK=32; LDS 32KB ->
// 5 blocks/CU; grid 512x3 with XCD swizzle (panel groups of 4 consecutive
// bids co-XCD). 2-phase: stage k+1 before compute k, vmcnt(4).
//  z=0: Qb[M,512] = Qin_b @ Wq     z=1: Kb = KVin_b @ Wk
//  z=2: Vt[512,M] = Wv^T . kv^T    (A=Wvt, B=KVin_b)
// ---------------------------------------------------------------------------
__global__ __launch_bounds__(256, 2) void gemm_qkv(const u16* __restrict__ Qin,
                                                   const u16* __restrict__ KVin,
                                                   const u16* __restrict__ Wqt,
                                                   const u16* __restrict__ Wkt,
                                                   const u16* __restrict__ Wvt,
                                                   u16* __restrict__ Qb,
                                                   u16* __restrict__ Kb,
                                                   u16* __restrict__ Vt) {
  __shared__ __attribute__((aligned(16))) u16 As[2][128 * 32];   // 2 x 8 KB
  __shared__ __attribute__((aligned(16))) u16 Bs[2][128 * 32];   // 2 x 8 KB
  const int tid = threadIdx.x;
  const int lane = tid & 63;
  const int w = tid >> 6;
  const int l15 = lane & 15;
  const int quad = lane >> 4;
  const int z = blockIdx.z;
  const int d = blockIdx.x;                  // 0..511
  const int bid = (d & 7) * 64 + (d >> 3);   // XCD swizzle, bijective on 512
  const int wr = (w >> 1) * 64, wc = (w & 1) * 64;
  const int srow = lane >> 2;
  const int scol = (lane & 3) * 8;

  int gm, gn;
  const u16 *A, *B;
  if (z < 2) {
    gm = (bid >> 2) * 128;  gn = (bid & 3) * 128;     // 128 m-tiles x 4 n-tiles
    A = z ? KVin : Qin;  B = z ? Wkt : Wqt;
  } else {
    gm = (bid & 3) * 128;   gn = (bid >> 2) * 128;    // 4 m-tiles x 128 n-tiles
    A = Wvt; B = KVin;
  }

  f32x4 acc[4][4] = {};

  // stage K-step kk into buffer b: 4 GLL16 per wave (2 A + 2 B)
  auto stage = [&](int kk, int b) {
    const int k0 = kk * 32;
#pragma unroll
    for (int i = 0; i < 2; i++) {
      int r0 = w * 32 + i * 16;
      GLL16(&A[(size_t)(gm + r0 + srow) * DIM + k0 + scol], &As[b][r0 * 32]);
      GLL16(&B[(size_t)(gn + r0 + srow) * DIM + k0 + scol], &Bs[b][r0 * 32]);
    }
  };

  stage(0, 0);
  for (int kk = 0; kk < 16; kk++) {
    const int cur = kk & 1;
    if (kk < 15) {
      stage(kk + 1, cur ^ 1);
      WAIT_VM_BAR("4");          // tile kk ready; tile kk+1 stays in flight
    } else {
      WAIT_VM_BAR("0");
    }

    bf16x8 af[4], bfr[4];
#pragma unroll
    for (int mt = 0; mt < 4; mt++)
      af[mt] = *reinterpret_cast<const bf16x8*>(&As[cur][(wr + mt * 16 + l15) * 32 + quad * 8]);
#pragma unroll
    for (int nt = 0; nt < 4; nt++)
      bfr[nt] = *reinterpret_cast<const bf16x8*>(&Bs[cur][(wc + nt * 16 + l15) * 32 + quad * 8]);
#pragma unroll
    for (int mt = 0; mt < 4; mt++)
#pragma unroll
      for (int nt = 0; nt < 4; nt++)
        acc[mt][nt] = __builtin_amdgcn_mfma_f32_16x16x32_bf16(af[mt], bfr[nt], acc[mt][nt], 0, 0, 0);

    LGKM_BAR();                  // ds_reads done before buffer reuse; no vm drain
  }

  if (z < 2) {
    u16* C = (z == 0) ? Qb : Kb;
#pragma unroll
    for (int mt = 0; mt < 4; mt++)
#pragma unroll
      for (int nt = 0; nt < 4; nt++)
#pragma unroll
        for (int r = 0; r < 4; r++)
          C[(size_t)(gm + wr + mt * 16 + quad * 4 + r) * DIM + gn + wc + nt * 16 + l15] = f2b(acc[mt][nt][r]);
  } else {
#pragma unroll
    for (int mt = 0; mt < 4; mt++)
#pragma unroll
      for (int nt = 0; nt < 4; nt++)
#pragma unroll
        for (int r = 0; r < 4; r++)
          Vt[(size_t)(gm + wr + mt * 16 + quad * 4 + r) * M_ROWS + gn + wc + nt * 16 + l15] = f2b(acc[mt][nt][r]);
  }
}

// ---------------------------------------------------------------------------
// Kernel 2: flash attention — R9 VERBATIM (GLL16 single-buffer KVBLK=64,
// per-g Pq planes, no fences, XCD swizzle, static-base exp2 softmax).
// ---------------------------------------------------------------------------
__global__ __launch_bounds__(256) void attn(const u16* __restrict__ Qb,
                                            const u16* __restrict__ Kb,
                                            const u16* __restrict__ Vtg,
                                            u16* __restrict__ Ob) {
  __shared__ __attribute__((aligned(16))) u16 Ks[2 * 64 * 32];    // [kd-plane][key][32]
  __shared__ __attribute__((aligned(16))) u16 Vs[2 * 64 * 32];    // [key-plane][d][32]
  __shared__ __attribute__((aligned(16))) u16 Pq[4][2][16 * 72];  // per-wave, per-g

  const int tid = threadIdx.x;
  const int lane = tid & 63;
  const int w = tid >> 6;
  const int l15 = lane & 15;
  const int quad = lane >> 4;
  const int srow = lane >> 2;
  const int scol = (lane & 3) * 8;

  // XCD swizzle: hw index d -> logical bid = (d&7)*128 + (d>>3). Bijective on
  // [0,1024). Panel group {4p..4p+3} maps to hw indices differing by 8 ->
  // same XCD under round-robin dispatch. Perf-only (any mapping is correct).
  const int d = blockIdx.x;
  const int bid = (d & 7) * 128 + (d >> 3);
  const int qt = bid & 3;            // 4 q-tiles of 128 rows
  const int bhp = bid >> 2;
  const int h = bhp & 7;
  const int bp = bhp >> 3;           // 0..31
  const int qrow0 = bp * SEQ + qt * 128;
  const int col0 = h * DHEAD;

  const float SCL = 0.18033688011112042f;   // 0.125 * log2(e)

  // Q fragments direct from global (B-operand layout: lane holds q=l15)
  bf16x8 qf[2][2];
#pragma unroll
  for (int g = 0; g < 2; g++)
#pragma unroll
    for (int kd = 0; kd < 2; kd++)
      qf[g][kd] = *reinterpret_cast<const bf16x8*>(
          &Qb[(size_t)(qrow0 + w * 32 + g * 16 + l15) * DIM + col0 + kd * 32 + quad * 8]);

  float l_[2] = {0.0f, 0.0f};
  f32x4 o[2][4] = {};

  for (int j = 0; j < 8; j++) {
    __syncthreads();
    const int krow0 = bp * SEQ + j * 64;
    // K staging: 8 GLL16 (plane=kd 0..1, 16-key chunk 0..3); wave w: t=2w..2w+1
#pragma unroll
    for (int i = 0; i < 2; i++) {
      int t = w * 2 + i;
      int plane = t & 1, chunk = t >> 1;
      GLL16(&Kb[(size_t)(krow0 + chunk * 16 + srow) * DIM + col0 + plane * 32 + scol],
            &Ks[plane * 2048 + chunk * 512]);
    }
    // V staging: 8 GLL16 (plane=32-key chunk 0..1, chunk=16-d chunk 0..3)
#pragma unroll
    for (int i = 0; i < 2; i++) {
      int t = w * 2 + i;
      int plane = t & 1, chunk = t >> 1;
      GLL16(&Vtg[(size_t)(col0 + chunk * 16 + srow) * M_ROWS + krow0 + plane * 32 + scol],
            &Vs[plane * 2048 + chunk * 512]);
    }
    __syncthreads();

#pragma unroll
    for (int g = 0; g < 2; g++) {
      // S^T = K*Q^T : 4 key-tiles of 16; D[key][q=l15]; scale has log2e folded
      f32x4 st[4];
#pragma unroll
      for (int ct = 0; ct < 4; ct++) {
        f32x4 z = {};
#pragma unroll
        for (int kd = 0; kd < 2; kd++) {
          bf16x8 kf = *reinterpret_cast<const bf16x8*>(&Ks[kd * 2048 + (ct * 16 + l15) * 32 + quad * 8]);
          z = __builtin_amdgcn_mfma_f32_16x16x32_bf16(kf, qf[g][kd], z, 0, 0, 0);
        }
        st[ct] = z * SCL;
      }

      // static-base softmax: P = 2^st directly (no max track, no rescale);
      // row-sum reduced across quads (q=l15 holds 16 keys/lane)
      float rs = 0.0f;
#pragma unroll
      for (int ct = 0; ct < 4; ct++)
#pragma unroll
        for (int r = 0; r < 4; r++) {
          float pv = __builtin_amdgcn_exp2f(st[ct][r]);
          st[ct][r] = pv;
          rs += pv;
        }
      rs += __shfl_xor(rs, 16);
      rs += __shfl_xor(rs, 32);
      l_[g] += rs;

      // P^T (C-layout) -> Pq[w][g][q][key], packed b64 stores. No fence:
      // per-g buffer => no reuse hazard; same-wave store->read ordering is
      // a visible data dependence the compiler handles with lgkmcnt(N).
#pragma unroll
      for (int ct = 0; ct < 4; ct++) {
        u16x4 pk;
#pragma unroll
        for (int e = 0; e < 4; e++) pk[e] = f2b(st[ct][e]);
        *reinterpret_cast<u16x4*>(&Pq[w][g][l15 * 72 + ct * 16 + quad * 4]) = pk;
      }

      // O += P*V : A = Pq[w][g][q=l15][key], B = Vs plane c2 [d][key-chunk]
#pragma unroll
      for (int c2 = 0; c2 < 2; c2++) {
        bf16x8 af = *reinterpret_cast<const bf16x8*>(&Pq[w][g][l15 * 72 + c2 * 32 + quad * 8]);
#pragma unroll
        for (int nt = 0; nt < 4; nt++) {
          bf16x8 bv = *reinterpret_cast<const bf16x8*>(&Vs[c2 * 2048 + (nt * 16 + l15) * 32 + quad * 8]);
          o[g][nt] = __builtin_amdgcn_mfma_f32_16x16x32_bf16(af, bv, o[g][nt], 0, 0, 0);
        }
      }
    }
  }

  // epilogue: normalize and write bf16 [M,512]
#pragma unroll
  for (int g = 0; g < 2; g++) {
    float inv = 1.0f / l_[g];
#pragma unroll
    for (int r = 0; r < 4; r++) {
      float lr = __shfl(inv, quad * 4 + r);
      int row = qrow0 + w * 32 + g * 16 + quad * 4 + r;
#pragma unroll
      for (int nt = 0; nt < 4; nt++)
        Ob[(size_t)row * DIM + col0 + nt * 16 + l15] = f2b(o[g][nt][r] * lr);
    }
  }
}

// ---------------------------------------------------------------------------
// Kernel 3: output GEMM, 2-phase double-buffered staging + XCD swizzle
// (1-D grid 512; blocks sharing an Ob A-panel were consecutive in x).
// fp32 epilogue + bias.
// ---------------------------------------------------------------------------
__global__ __launch_bounds__(256) void gemm_out(const u16* __restrict__ Ab,
                                                const u16* __restrict__ Bt,
                                                const float* __restrict__ bias,
                                                float* __restrict__ C) {
  __shared__ __attribute__((aligned(16))) u16 As[2][128 * 32];
  __shared__ __attribute__((aligned(16))) u16 Bs[2][128 * 32];
  const int tid = threadIdx.x;
  const int lane = tid & 63;
  const int w = tid >> 6;
  const int l15 = lane & 15;
  const int quad = lane >> 4;
  const int d = blockIdx.x;                  // 0..511
  const int bid = (d & 7) * 64 + (d >> 3);   // XCD swizzle, bijective on 512
  const int gn = (bid & 3) * 128;
  const int gm = (bid >> 2) * 128;
  const int wr = (w >> 1) * 64, wc = (w & 1) * 64;
  const int srow = lane >> 2;
  const int scol = (lane & 3) * 8;

  f32x4 acc[4][4] = {};

  // stage K-step kk into buffer b: 4 GLL16 per wave (2 A + 2 B)
  auto stage = [&](int kk, int b) {
    const int k0 = kk * 32;
#pragma unroll
    for (int i = 0; i < 2; i++) {
      int r0 = w * 32 + i * 16;
      GLL16(&Ab[(size_t)(gm + r0 + srow) * DIM + k0 + scol], &As[b][r0 * 32]);
      GLL16(&Bt[(size_t)(gn + r0 + srow) * DIM + k0 + scol], &Bs[b][r0 * 32]);
    }
  };

  stage(0, 0);
  for (int kk = 0; kk < 16; kk++) {
    const int cur = kk & 1;
    if (kk < 15) {
      stage(kk + 1, cur ^ 1);
      WAIT_VM_BAR("4");
    } else {
      WAIT_VM_BAR("0");
    }

    bf16x8 af[4], bfr[4];
#pragma unroll
    for (int mt = 0; mt < 4; mt++)
      af[mt] = *reinterpret_cast<const bf16x8*>(&As[cur][(wr + mt * 16 + l15) * 32 + quad * 8]);
#pragma unroll
    for (int nt = 0; nt < 4; nt++)
      bfr[nt] = *reinterpret_cast<const bf16x8*>(&Bs[cur][(wc + nt * 16 + l15) * 32 + quad * 8]);
#pragma unroll
    for (int mt = 0; mt < 4; mt++)
#pragma unroll
      for (int nt = 0; nt < 4; nt++)
        acc[mt][nt] = __builtin_amdgcn_mfma_f32_16x16x32_bf16(af[mt], bfr[nt], acc[mt][nt], 0, 0, 0);

    LGKM_BAR();
  }

#pragma unroll
  for (int mt = 0; mt < 4; mt++)
#pragma unroll
    for (int nt = 0; nt < 4; nt++) {
      float bcol = bias[gn + wc + nt * 16 + l15];
#pragma unroll
      for (int r = 0; r < 4; r++)
        C[(size_t)(gm + wr + mt * 16 + quad * 4 + r) * DIM + gn + wc + nt * 16 + l15] = acc[mt][nt][r] + bcol;
    }
}

// ---------------------------------------------------------------------------
extern "C" void kernel_launch(void* const* d_in, const int* in_sizes, int n_in,
                              void* d_out, int out_size, void* d_ws, size_t ws_size,
                              hipStream_t stream) {
  const float* q_in  = (const float*)d_in[0];
  const float* kv_in = (const float*)d_in[1];
  const float* Wq    = (const float*)d_in[2];
  const float* Wk    = (const float*)d_in[3];
  const float* Wv    = (const float*)d_in[4];
  const float* Wo    = (const float*)d_in[5];
  const float* bo    = (const float*)d_in[6];
  float* out = (float*)d_out;

  u16* ws = (u16*)d_ws;
  u16* Wqt = ws;
  u16* Wkt = ws + 262144;
  u16* Wvt = ws + 524288;
  u16* Wot = ws + 786432;
  u16* Qb  = ws + 1048576;
  u16* Kb  = Qb + (size_t)M_ROWS * DIM;
  u16* Vtg = Kb + (size_t)M_ROWS * DIM;
  u16* Ob  = Vtg + (size_t)M_ROWS * DIM;
  // bf16 copies of the fp32 inputs live in d_out (dead before gemm_out writes it)
  u16* Qin_b  = (u16*)d_out;
  u16* KVin_b = Qin_b + (size_t)M_ROWS * DIM;

  prep<<<dim3(9216), 256, 0, stream>>>(q_in, kv_in, Wq, Wk, Wv, Wo, Qin_b, KVin_b, ws);
  gemm_qkv<<<dim3(512, 1, 3), 256, 0, stream>>>(Qin_b, KVin_b, Wqt, Wkt, Wvt, Qb, Kb, Vtg);
  attn<<<dim3(1024), 256, 0, stream>>>(Qb, Kb, Vtg, Ob);
  gemm_out<<<dim3(512), 256, 0, stream>>>(Ob, Wot, bo, out);
}